// Round 6
// baseline (134.839 us; speedup 1.0000x reference)
//
#include <hip/hip_runtime.h>
#include <hip/hip_bf16.h>

typedef unsigned int u32;
typedef unsigned short u16;

#define TOKENS 512
#define OUT_F  8192
#define IN_F   4096
#define KPACK  (IN_F / 4)
#define TMB 128              // block m-tile
#define TNB 64               // block n-tile (grid 512 = 2 blocks/CU)
#define BKW 128              // k per window
#define NWIN (IN_F / BKW)    // 32

typedef __attribute__((ext_vector_type(8))) short bf16x8;
typedef __attribute__((ext_vector_type(4))) float f32x4;
typedef __attribute__((ext_vector_type(16))) float f32x16;

__device__ __forceinline__ u32 pack_bf16x2(float a, float b) {
    __hip_bfloat162 h = __float22bfloat162_rn(make_float2(a, b));
    union { __hip_bfloat162 h2; u32 u; } cvt;
    cvt.h2 = h;
    return cvt.u;
}

// 2 codes (4 bits) -> 2 packed bf16 via byte-table v_perm.
// code 0 -> 0xBF80 (-1), 2 -> 0x3F80 (+1), 1/3 -> 0x0000.
__device__ __forceinline__ u32 decode_pair(u32 d) {
    u32 s = (__umul24(d, 0x808202u) & 0x06060606u) + 0x01000100u;
    return __builtin_amdgcn_perm(0x00003F80u, 0x0000BF80u, s);
}
// 16 bits (8 consecutive-k codes) at bit offset sh of w -> B fragment.
__device__ __forceinline__ bf16x8 decode_frag(u32 w, int sh) {
    union { bf16x8 v; u32 u[4]; } c;
    c.u[0] = decode_pair((w >> (sh + 0)) & 0xFu);
    c.u[1] = decode_pair((w >> (sh + 4)) & 0xFu);
    c.u[2] = decode_pair((w >> (sh + 8)) & 0xFu);
    c.u[3] = decode_pair((w >> (sh + 12)) & 0xFu);
    return c.v;
}

__device__ __forceinline__ void async_ld16(const void* g, void* l) {
    __builtin_amdgcn_global_load_lds(
        (const __attribute__((address_space(1))) u32*)g,
        (__attribute__((address_space(3))) u32*)l, 16, 0, 0);
}

// B prefetch via inline asm: deterministic FIFO position in the vmcnt queue.
// Dest VGPR is valid only after the matching s_waitcnt.
__device__ __forceinline__ void async_b(const u32* g, u32& dst) {
    asm volatile("global_load_dword %0, %1, off"
                 : "=v"(dst) : "v"(g) : "memory");
}

#define VMW(N) asm volatile("s_waitcnt vmcnt(" #N ")" ::: "memory")

// ---- fused pre-pass: repack (blockIdx.y<8) + X fp32->bf16 convert (y==8) ----
// Repack W2 -> dense 2-bit fragment-major, per-wave u32 streams (W9, R2 layout):
// W9 u32 idx = (((nb*4 + kq)*2 + nh)*NWIN + w)*64 + lane
//   nb = 64-col block (0..127); value = 16 codes (2 u16) for
//   col = nb*64 + nh*32 + (lane&31), k = w*128 + kq*32 + ksub*16 + (lane>>5)*8 .. +7
__global__ __launch_bounds__(256) void prep(const float* __restrict__ X,
                                            u16* __restrict__ Xb,
                                            const u32* __restrict__ W2,
                                            u32* __restrict__ W9) {
    __shared__ u32 dense[128 * 32];    // 16 KB; dense[col*32 + (j ^ (col&31))]
    const int t = threadIdx.x;

    if (blockIdx.y == 8) {
        // ---- convert: 64 blocks x 256 thr x 128 floats = 2M floats ----
        int base = blockIdx.x * 32768 + t * 8;
#pragma unroll
        for (int r = 0; r < 16; ++r) {
            int i = base + r * 2048;
            float4 a = *(const float4*)(X + i);
            float4 b = *(const float4*)(X + i + 4);
            uint4 q;
            q.x = pack_bf16x2(a.x, a.y);
            q.y = pack_bf16x2(a.z, a.w);
            q.z = pack_bf16x2(b.x, b.y);
            q.w = pack_bf16x2(b.z, b.w);
            *(uint4*)(Xb + i) = q;
        }
        return;
    }

    const int ngrp = blockIdx.x;       // 64 col-groups of 128
    const int kc   = blockIdx.y;       // 8 k-chunks of 512 codes (4 windows)
#pragma unroll
    for (int i = 0; i < 16; ++i) {     // phase 1: coalesced uint4 reads
        int id = t + 256 * i;
        int col = id >> 5, jq = id & 31;
        uint4 wv = *(const uint4*)(W2 + (size_t)(ngrp * 128 + col) * KPACK + kc * 128 + jq * 4);
        dense[col * 32 + (jq ^ (col & 31))] =
            (wv.x & 0xFFu) | ((wv.y & 0xFFu) << 8) | ((wv.z & 0xFFu) << 16) | ((wv.w & 0xFFu) << 24);
    }
    __syncthreads();
    const u16* sp = (const u16*)dense;
#pragma unroll
    for (int p = 0; p < 4; ++p) {      // phase 2: per-stream coalesced u32 writes
        int e = t + 256 * p;           // 0..1023
        int lane = e & 63;
        int kq = (e >> 6) & 3;
        int wp2 = (e >> 8) & 1;        // window-pair within this kc
        int nho = (e >> 9) & 1;        // which 64-col half of the 128-col group
        int h = lane >> 5;
        int c0 = nho * 64 + (lane & 31), c1 = c0 + 32;
        int nb = ngrp * 2 + nho;
#pragma unroll
        for (int ws = 0; ws < 2; ++ws) {
            int wloc = wp2 * 2 + ws;
            int w = kc * 4 + wloc;
            int j0 = wloc * 8 + kq * 2;
            u32 x0 = sp[((c0 * 32 + (j0 ^ (c0 & 31))) << 1) | h];
            u32 x1 = sp[((c0 * 32 + ((j0 + 1) ^ (c0 & 31))) << 1) | h];
            u32 y0 = sp[((c1 * 32 + (j0 ^ (c1 & 31))) << 1) | h];
            u32 y1 = sp[((c1 * 32 + ((j0 + 1) ^ (c1 & 31))) << 1) | h];
            W9[((((size_t)nb * 4 + kq) * 2 + 0) * NWIN + w) * 64 + lane] = x0 | (x1 << 16);
            W9[((((size_t)nb * 4 + kq) * 2 + 1) * NWIN + w) * 64 + lane] = y0 | (y1 << 16);
        }
    }
}

// ---- main GEMM: the untried cell of the {blocks/CU} x {drain|counted} matrix:
//      TWO blocks/CU (R2 geometry: 128x64 tile, 512 thr, 8 waves = 4 kq x 2 nh,
//      64 KB LDS, ~120 unified regs forced by __launch_bounds__(512,4))
//      + R3-proven counted-vmcnt pipeline (2 A-buffers, A issued post-barrier
//      depth-1, B in VGPRs depth-2, steady vmcnt(1), vmcnt(0) only at the
//      final peeled window; one sched_barrier(0) per window; NO setprio). ----
__global__ __launch_bounds__(512, 4) void ternary_gemm13(
    const u16* __restrict__ Xb,
    const u32* __restrict__ W9,
    const float* __restrict__ alpha,
    const float* __restrict__ bias,
    float* __restrict__ Out)
{
    __shared__ u16 As[2][TMB * BKW];   // 2 x 32 KB; As[0] reused as reduction scratch

    const int tid  = threadIdx.x;
    const int lane = tid & 63;
    const int wave = tid >> 6;
    const int kq = wave & 3;           // k-quarter (32 of each 128-k window)
    const int nh = wave >> 2;          // n-half (32 cols)

    const int m0 = blockIdx.x * TMB;
    const int nb = blockIdx.y;
    const int n0 = nb * TNB;

    f32x16 acc[4];
#pragma unroll
    for (int mt = 0; mt < 4; ++mt)
#pragma unroll
        for (int i = 0; i < 16; ++i)
            acc[mt][i] = 0.f;

    // A staging: wave stages rows [wave*16, wave*16+16), 4 insts x 4 rows.
    // Row = 128 k = 16 chunks of 16 B; chunk c stored at slot c ^ (row&15).
    // SGPR base + small per-lane u32 offsets (register diet, proven in R2).
    const u16* gbase = Xb + (size_t)(m0 + wave * 16) * IN_F;   // wave-uniform
    u32 aoff[4];
    u32 lbase[4];                                              // wave-uniform
#pragma unroll
    for (int i = 0; i < 4; ++i) {
        int rr = i * 4 + (lane >> 4);
        int cd = (lane & 15) ^ (rr & 15);
        aoff[i] = rr * IN_F + cd * 8;
        lbase[i] = (wave * 16 + i * 4) * BKW;
    }

    // A-fragment LDS offsets (u16 units); mt adds +32 rows = +8192 B (imm offset)
    u32 ofsA0[2];
#pragma unroll
    for (int ks = 0; ks < 2; ++ks) {
        int row = lane & 31;
        int chunk = kq * 4 + ks * 2 + (lane >> 5);
        ofsA0[ks] = row * BKW + (chunk ^ (row & 15)) * 8;
    }

    // B: one u32 per lane per window, contiguous per-wave stream.
    const u32* wq = W9 + ((((size_t)nb * 4 + kq) * 2 + nh) * NWIN) * 64 + lane;

    auto issueA = [&](int w) {
        u16* d = As[w & 1];
        const int koff = w * BKW;
#pragma unroll
        for (int i = 0; i < 4; ++i)
            async_ld16(gbase + aoff[i] + koff, d + lbase[i]);
    };

    auto window_compute = [&](int buf, u32 bw) {
        const u16* ab = As[buf];
#pragma unroll
        for (int ks = 0; ks < 2; ++ks) {
            const u16* ap = ab + ofsA0[ks];
            bf16x8 a0 = *(const bf16x8*)(ap);
            bf16x8 a1 = *(const bf16x8*)(ap + 4096);
            bf16x8 a2 = *(const bf16x8*)(ap + 8192);
            bf16x8 a3 = *(const bf16x8*)(ap + 12288);
            bf16x8 b0 = decode_frag(bw, ks * 16);
            acc[0] = __builtin_amdgcn_mfma_f32_32x32x16_bf16(a0, b0, acc[0], 0, 0, 0);
            acc[1] = __builtin_amdgcn_mfma_f32_32x32x16_bf16(a1, b0, acc[1], 0, 0, 0);
            acc[2] = __builtin_amdgcn_mfma_f32_32x32x16_bf16(a2, b0, acc[2], 0, 0, 0);
            acc[3] = __builtin_amdgcn_mfma_f32_32x32x16_bf16(a3, b0, acc[3], 0, 0, 0);
        }
    };

    // Prologue, exact FIFO order: B(0), A(0)x4, B(1)  -> 6 in flight.
    u32 bqE, bqO;
    async_b(wq, bqE);
    issueA(0);
    async_b(wq + 64, bqO);

    // Window body: VMW(1) retires oldest 5 (= B(w), A(w)x4), keeps B(w+1);
    // barrier certifies all waves' A(w) DMAs -> buffer w readable; single
    // sched_barrier(0) fences the decode against hoisting above the wait
    // (rule #18). issueA(w+1) post-barrier into buf (w+1)&1 is race-free:
    // that buffer's last reader was compute(w-1), pre-barrier for all waves.
#pragma unroll 1
    for (int p = 0; p < (NWIN - 2) / 2; ++p) {   // windows 0..29
        const int w = 2 * p;
        VMW(1);
        __builtin_amdgcn_s_barrier();
        __builtin_amdgcn_sched_barrier(0);
        issueA(w + 1);
        window_compute(0, bqE);
        async_b(wq + (size_t)(w + 2) * 64, bqE);

        VMW(1);
        __builtin_amdgcn_s_barrier();
        __builtin_amdgcn_sched_barrier(0);
        issueA(w + 2);
        window_compute(1, bqO);
        async_b(wq + (size_t)(w + 3) * 64, bqO);
    }
    // w = 30: outstanding = B(30), A(30)x4, B(31) = 6 -> keep 1.
    VMW(1);
    __builtin_amdgcn_s_barrier();
    __builtin_amdgcn_sched_barrier(0);
    issueA(31);
    window_compute(0, bqE);
    // w = 31: final drain (B(31), A(31)x4 outstanding).
    VMW(0);
    __builtin_amdgcn_s_barrier();
    __builtin_amdgcn_sched_barrier(0);
    window_compute(1, bqO);

    // ---- 4-way kq reduction through LDS (3 staggered rounds, 32 KB scratch) ----
    // Scratch = As[0] (buf 0): last read at window 30, complete before the
    // w=31 barrier for all waves; all DMAs drained by the final vmcnt(0).
    // Concurrent compute(31) reads buf 1 only — disjoint.
    f32x4* red = (f32x4*)As;           // 2048 f32x4 = 32 KB (fits in As[0])
#pragma unroll 1
    for (int q = 1; q < 4; ++q) {
        if (kq == q) {
            f32x4* dst = red + nh * 1024 + lane;
#pragma unroll
            for (int mt = 0; mt < 4; ++mt)
#pragma unroll
                for (int sub = 0; sub < 4; ++sub) {
                    f32x4 v = {acc[mt][sub * 4 + 0], acc[mt][sub * 4 + 1],
                               acc[mt][sub * 4 + 2], acc[mt][sub * 4 + 3]};
                    dst[(mt * 4 + sub) * 64] = v;
                }
        }
        __syncthreads();
        if (kq == 0) {
            const f32x4* src = red + nh * 1024 + lane;
#pragma unroll
            for (int mt = 0; mt < 4; ++mt)
#pragma unroll
                for (int sub = 0; sub < 4; ++sub) {
                    f32x4 v = src[(mt * 4 + sub) * 64];
#pragma unroll
                    for (int i = 0; i < 4; ++i)
                        acc[mt][sub * 4 + i] += v[i];
                }
        }
        __syncthreads();
    }

    // ---- epilogue (kq==0 waves): alpha*acc + bias ----
    if (kq == 0) {
        int ncol = n0 + nh * 32 + (lane & 31);
        float av = alpha[ncol];
        float bv = bias[ncol];
#pragma unroll
        for (int mt = 0; mt < 4; ++mt) {
#pragma unroll
            for (int r = 0; r < 16; ++r) {
                int row = m0 + mt * 32 + (r & 3) + 8 * (r >> 2) + 4 * (lane >> 5);
                Out[(size_t)row * OUT_F + ncol] = acc[mt][r] * av + bv;
            }
        }
    }
}

// ---- naive fallback (workspace too small; correctness only) ----
__global__ void ternary_naive(const float* __restrict__ X, const u32* __restrict__ W2,
                              const float* __restrict__ alpha, const float* __restrict__ bias,
                              float* __restrict__ Out) {
    int o  = blockIdx.x * 64 + (threadIdx.x & 63);
    int tk = blockIdx.y * 4 + (threadIdx.x >> 6);
    const float* x = X + (size_t)tk * IN_F;
    const u32* w = W2 + (size_t)o * KPACK;
    float s = 0.f;
    for (int d = 0; d < KPACK; ++d) {
        u32 b = w[d] & 0xFFu;
        const float* xp = x + d * 4;
#pragma unroll
        for (int j = 0; j < 4; ++j) {
            u32 c = (b >> (2 * j)) & 3u;
            float wv = (c == 2u) ? 1.f : ((c == 0u) ? -1.f : 0.f);
            s += xp[j] * wv;
        }
    }
    Out[(size_t)tk * OUT_F + o] = s * alpha[o] + bias[o];
}

extern "C" void kernel_launch(void* const* d_in, const int* in_sizes, int n_in,
                              void* d_out, int out_size, void* d_ws, size_t ws_size,
                              hipStream_t stream) {
    const float* x = (const float*)d_in[0];
    const u32* w2 = (const u32*)d_in[1];
    const float* alpha = (const float*)d_in[2];
    const float* bias  = (const float*)d_in[3];
    float* out = (float*)d_out;

    const size_t xb_bytes = (size_t)TOKENS * IN_F * sizeof(u16);   // 4 MB
    const size_t w9_bytes = (size_t)OUT_F * IN_F / 4;              // 8 MB

    if (ws_size >= xb_bytes + w9_bytes) {
        u16* xb = (u16*)d_ws;
        u32* w9 = (u32*)((char*)d_ws + xb_bytes);
        prep<<<dim3(64, 9), 256, 0, stream>>>(x, xb, w2, w9);
        ternary_gemm13<<<dim3(TOKENS / TMB, OUT_F / TNB), 512, 0, stream>>>(xb, w9, alpha, bias, out);
    } else {
        ternary_naive<<<dim3(OUT_F / 64, TOKENS / 4), 256, 0, stream>>>(x, w2, alpha, bias, out);
    }
}

// Round 7
// 126.497 us; speedup vs baseline: 1.0660x; 1.0660x over previous
//
#include <hip/hip_runtime.h>
#include <hip/hip_bf16.h>

typedef unsigned int u32;
typedef unsigned short u16;

#define TOKENS 512
#define OUT_F  8192
#define IN_F   4096
#define KPACK  (IN_F / 4)
#define TMB 128              // block m-tile
#define TNB 128              // block n-tile
#define BKW 256              // k per window (doubled: halves per-window overhead count)
#define NWIN (IN_F / BKW)    // 16

typedef __attribute__((ext_vector_type(8))) short bf16x8;
typedef __attribute__((ext_vector_type(4))) float f32x4;
typedef __attribute__((ext_vector_type(16))) float f32x16;

__device__ __forceinline__ u32 pack_bf16x2(float a, float b) {
    __hip_bfloat162 h = __float22bfloat162_rn(make_float2(a, b));
    union { __hip_bfloat162 h2; u32 u; } cvt;
    cvt.h2 = h;
    return cvt.u;
}

// 2 codes (4 bits) -> 2 packed bf16 via byte-table v_perm.
// code 0 -> 0xBF80 (-1), 2 -> 0x3F80 (+1), 1/3 -> 0x0000.
__device__ __forceinline__ u32 decode_pair(u32 d) {
    u32 s = (__umul24(d, 0x808202u) & 0x06060606u) + 0x01000100u;
    return __builtin_amdgcn_perm(0x00003F80u, 0x0000BF80u, s);
}
// 16 bits (8 consecutive-k codes) at bit offset sh of w -> B fragment.
__device__ __forceinline__ bf16x8 decode_frag(u32 w, int sh) {
    union { bf16x8 v; u32 u[4]; } c;
    c.u[0] = decode_pair((w >> (sh + 0)) & 0xFu);
    c.u[1] = decode_pair((w >> (sh + 4)) & 0xFu);
    c.u[2] = decode_pair((w >> (sh + 8)) & 0xFu);
    c.u[3] = decode_pair((w >> (sh + 12)) & 0xFu);
    return c.v;
}

__device__ __forceinline__ void async_ld16(const void* g, void* l) {
    __builtin_amdgcn_global_load_lds(
        (const __attribute__((address_space(1))) u32*)g,
        (__attribute__((address_space(3))) u32*)l, 16, 0, 0);
}

// B prefetch via inline asm: deterministic FIFO position in the vmcnt queue.
// Dest VGPRs are valid only after the matching s_waitcnt.
__device__ __forceinline__ void async_b4(const uint4* g, uint4& dst) {
    asm volatile("global_load_dwordx4 %0, %1, off"
                 : "=v"(dst) : "v"(g) : "memory");
}

#define VMW(N) asm volatile("s_waitcnt vmcnt(" #N ")" ::: "memory")

// ---- fused pre-pass: repack (blockIdx.y<8) + X fp32->bf16 convert (y==8) ----
// Repack W2 -> dense 2-bit fragment-major, window-256 uint4 streams (W10):
// W10 uint4 idx = (((ngrp*2+nh)*4 + kq)*NWIN + w)*64 + lane
//  .x = u16 fields ks=0,1 for nt=0 ; .y = ks=2,3 nt=0 ; .z/.w same for nt=1
//  field(ks): 8 codes, col = ngrp*128 + nh*64 + nt*32 + (lane&31),
//             k = w*256 + kq*64 + ks*16 + (lane>>5)*8 .. +7
__global__ __launch_bounds__(256) void prep(const float* __restrict__ X,
                                            u16* __restrict__ Xb,
                                            const u32* __restrict__ W2,
                                            uint4* __restrict__ W10) {
    __shared__ u32 dense[128 * 32];    // 16 KB; dense[col*32 + (j ^ (col&31))]
    const int t = threadIdx.x;

    if (blockIdx.y == 8) {
        // ---- convert: 64 blocks x 256 thr x 128 floats = 2M floats ----
        int base = blockIdx.x * 32768 + t * 8;
#pragma unroll
        for (int r = 0; r < 16; ++r) {
            int i = base + r * 2048;
            float4 a = *(const float4*)(X + i);
            float4 b = *(const float4*)(X + i + 4);
            uint4 q;
            q.x = pack_bf16x2(a.x, a.y);
            q.y = pack_bf16x2(a.z, a.w);
            q.z = pack_bf16x2(b.x, b.y);
            q.w = pack_bf16x2(b.z, b.w);
            *(uint4*)(Xb + i) = q;
        }
        return;
    }

    const int ngrp = blockIdx.x;       // 64 col-groups of 128
    const int kc   = blockIdx.y;       // 8 k-chunks of 512 codes (2 windows of 256)
#pragma unroll
    for (int i = 0; i < 16; ++i) {     // phase 1: coalesced uint4 reads
        int id = t + 256 * i;
        int col = id >> 5, jq = id & 31;
        uint4 wv = *(const uint4*)(W2 + (size_t)(ngrp * 128 + col) * KPACK + kc * 128 + jq * 4);
        dense[col * 32 + (jq ^ (col & 31))] =
            (wv.x & 0xFFu) | ((wv.y & 0xFFu) << 8) | ((wv.z & 0xFFu) << 16) | ((wv.w & 0xFFu) << 24);
    }
    __syncthreads();
    const u16* sp = (const u16*)dense;
#pragma unroll
    for (int p = 0; p < 4; ++p) {      // phase 2: coalesced uint4 writes
        int e = t + 256 * p;           // 0..1023
        int lane = e & 63;
        int kq = (e >> 6) & 3;
        int nh = (e >> 8) & 1;
        int wloc = (e >> 9) & 1;       // window within this kc (w = kc*2 + wloc)
        int h = lane >> 5;
        int c0 = nh * 64 + (lane & 31), c1 = c0 + 32;
        u32 f[4], g[4];
#pragma unroll
        for (int ks = 0; ks < 4; ++ks) {
            int j = wloc * 16 + kq * 4 + ks;
            f[ks] = sp[((c0 * 32 + (j ^ (c0 & 31))) << 1) | h];
            g[ks] = sp[((c1 * 32 + (j ^ (c1 & 31))) << 1) | h];
        }
        uint4 o;
        o.x = f[0] | (f[1] << 16);
        o.y = f[2] | (f[3] << 16);
        o.z = g[0] | (g[1] << 16);
        o.w = g[2] | (g[3] << 16);
        int w = kc * 2 + wloc;
        W10[(((size_t)(ngrp * 2 + nh) * 4 + kq) * NWIN + w) * 64 + lane] = o;
    }
}

// ---- main GEMM: 128x128 block, 512 thr, 8 waves = 4 kq x 2 nh, mt=4,
//      BKW=256 windows (16 total): halves the count of per-window fixed costs
//      (post-barrier LDS-latency refill, phase lockstep, barrier skew) that
//      pinned MfmaUtil at ~30% across 4 structural variants (R0/R2/R5/R6).
//      Counted-vmcnt skeleton (R5/R6-proven): 2 A-buffers (128 KB LDS),
//      depth-1 A issued post-barrier pre-compute, B uint4 in VGPRs depth-2,
//      steady vmcnt(1), vmcnt(0) only at the peeled final window,
//      one sched_barrier(0) per window, NO setprio. ----
__global__ __launch_bounds__(512, 2) void ternary_gemm14(
    const u16* __restrict__ Xb,
    const uint4* __restrict__ W10,
    const float* __restrict__ alpha,
    const float* __restrict__ bias,
    float* __restrict__ Out)
{
    __shared__ u16 As[2][TMB * BKW];   // 2 x 64 KB; As[0] reused as reduction scratch

    const int tid  = threadIdx.x;
    const int lane = tid & 63;
    const int wave = tid >> 6;
    const int kq = wave & 3;           // k-quarter (64 of each 256-k window)
    const int nh = wave >> 2;          // n-half (64 cols)

    const int m0 = blockIdx.x * TMB;
    const int ngrp = blockIdx.y;
    const int n0 = ngrp * TNB;

    f32x16 acc[4][2];
#pragma unroll
    for (int mt = 0; mt < 4; ++mt)
#pragma unroll
        for (int nt = 0; nt < 2; ++nt)
#pragma unroll
            for (int i = 0; i < 16; ++i)
                acc[mt][nt][i] = 0.f;

    // A staging: wave stages rows [wave*16, wave*16+16), 8 insts x 2 rows.
    // Row = 256 k = 32 chunks of 16 B; chunk c stored at slot
    // ((c&15) ^ (row&15)) | (c&16)  — swizzle within each 16-chunk group
    // (preserves R5's measured conflict-free read pattern; group bit linear).
    // DMA dest is linear (slot = lane&31, row = lane>>5), so the swizzle is
    // applied on the per-lane GLOBAL source address (m173 pattern).
    const u16* gbase = Xb + (size_t)(m0 + wave * 16) * IN_F;   // wave-uniform
    u32 aoff[8];
    u32 lbase[8];                                              // wave-uniform
#pragma unroll
    for (int i = 0; i < 8; ++i) {
        int rr = i * 2 + (lane >> 5);                          // 0..15
        int cd = ((lane & 15) ^ (rr & 15)) | (lane & 16);
        aoff[i] = rr * IN_F + cd * 8;
        lbase[i] = (wave * 16 + i * 2) * BKW;
    }

    // A-fragment LDS offsets (u16 units); mt adds +32 rows = +8192 u16
    // (16384 B imm, max 49152 B < 64 KB imm field).
    u32 ofsA0[4];
#pragma unroll
    for (int ks = 0; ks < 4; ++ks) {
        int row = lane & 31;
        int chunk = kq * 8 + ks * 2 + (lane >> 5);             // 0..31
        int slot = ((chunk & 15) ^ (row & 15)) | (chunk & 16);
        ofsA0[ks] = row * BKW + slot * 8;
    }

    // B: one uint4 per lane per window, contiguous per-wave stream.
    const uint4* wq = W10 + (((size_t)(ngrp * 2 + nh) * 4 + kq) * NWIN) * 64 + lane;

    auto issueA = [&](int w) {
        u16* d = As[w & 1];
        const int koff = w * BKW;
#pragma unroll
        for (int i = 0; i < 8; ++i)
            async_ld16(gbase + aoff[i] + koff, d + lbase[i]);
    };

    auto window_compute = [&](int buf, uint4 bq) {
        const u16* ab = As[buf];
#pragma unroll
        for (int ks = 0; ks < 4; ++ks) {
            const u16* ap = ab + ofsA0[ks];
            bf16x8 a0 = *(const bf16x8*)(ap);
            bf16x8 a1 = *(const bf16x8*)(ap + 8192);
            bf16x8 a2 = *(const bf16x8*)(ap + 16384);
            bf16x8 a3 = *(const bf16x8*)(ap + 24576);
            u32 wx = (ks < 2) ? bq.x : bq.y;                   // nt=0
            u32 wz = (ks < 2) ? bq.z : bq.w;                   // nt=1
            const int sh = (ks & 1) * 16;
            bf16x8 b0 = decode_frag(wx, sh);
            bf16x8 b1 = decode_frag(wz, sh);
            acc[0][0] = __builtin_amdgcn_mfma_f32_32x32x16_bf16(a0, b0, acc[0][0], 0, 0, 0);
            acc[1][0] = __builtin_amdgcn_mfma_f32_32x32x16_bf16(a1, b0, acc[1][0], 0, 0, 0);
            acc[2][0] = __builtin_amdgcn_mfma_f32_32x32x16_bf16(a2, b0, acc[2][0], 0, 0, 0);
            acc[3][0] = __builtin_amdgcn_mfma_f32_32x32x16_bf16(a3, b0, acc[3][0], 0, 0, 0);
            acc[0][1] = __builtin_amdgcn_mfma_f32_32x32x16_bf16(a0, b1, acc[0][1], 0, 0, 0);
            acc[1][1] = __builtin_amdgcn_mfma_f32_32x32x16_bf16(a1, b1, acc[1][1], 0, 0, 0);
            acc[2][1] = __builtin_amdgcn_mfma_f32_32x32x16_bf16(a2, b1, acc[2][1], 0, 0, 0);
            acc[3][1] = __builtin_amdgcn_mfma_f32_32x32x16_bf16(a3, b1, acc[3][1], 0, 0, 0);
        }
    };

    // Prologue, exact FIFO order: B(0), A(0)x8, B(1)  -> 10 in flight.
    uint4 bqE, bqO;
    async_b4(wq, bqE);
    issueA(0);
    async_b4(wq + 64, bqO);

    // Window body: VMW(1) retires oldest 9 (= B(w), A(w)x8), keeps B(w+1);
    // barrier certifies all waves' A(w) DMAs -> buffer w readable; single
    // sched_barrier(0) fences the decode/ds_read against hoisting above the
    // wait (rule #18). issueA(w+1) post-barrier pre-compute (depth-1 needs
    // the full compute(w) to cover its L2 latency; R6-validated): buffer
    // (w+1)&1's last reader was compute(w-1), pre-barrier for all waves.
#pragma unroll 1
    for (int p = 0; p < (NWIN - 2) / 2; ++p) {   // windows 0..13
        const int w = 2 * p;
        VMW(1);
        __builtin_amdgcn_s_barrier();
        __builtin_amdgcn_sched_barrier(0);
        issueA(w + 1);
        window_compute(0, bqE);
        async_b4(wq + (size_t)(w + 2) * 64, bqE);

        VMW(1);
        __builtin_amdgcn_s_barrier();
        __builtin_amdgcn_sched_barrier(0);
        issueA(w + 2);
        window_compute(1, bqO);
        async_b4(wq + (size_t)(w + 3) * 64, bqO);
    }
    // w = 14: outstanding = B(14), A(14)x8, B(15) = 10 -> keep 1.
    VMW(1);
    __builtin_amdgcn_s_barrier();
    __builtin_amdgcn_sched_barrier(0);
    issueA(15);
    window_compute(0, bqE);
    // w = 15: final drain (B(15), A(15)x8 outstanding).
    VMW(0);
    __builtin_amdgcn_s_barrier();
    __builtin_amdgcn_sched_barrier(0);
    window_compute(1, bqO);

    // ---- 4-way kq reduction through LDS (3 staggered rounds, 64 KB scratch) ----
    // Scratch = As[0] (buf 0): last read at window 14, complete before the
    // w=15 barrier for all waves; all DMAs drained by the final vmcnt(0).
    // Concurrent compute(15) reads buf 1 only — disjoint.
    f32x4* red = (f32x4*)As;           // 4096 f32x4 = 64 KB (fits in As[0])
#pragma unroll 1
    for (int q = 1; q < 4; ++q) {
        if (kq == q) {
            f32x4* dst = red + nh * 2048 + lane;
#pragma unroll
            for (int mt = 0; mt < 4; ++mt)
#pragma unroll
                for (int nt = 0; nt < 2; ++nt)
#pragma unroll
                    for (int sub = 0; sub < 4; ++sub) {
                        f32x4 v = {acc[mt][nt][sub * 4 + 0], acc[mt][nt][sub * 4 + 1],
                                   acc[mt][nt][sub * 4 + 2], acc[mt][nt][sub * 4 + 3]};
                        dst[(mt * 8 + nt * 4 + sub) * 64] = v;
                    }
        }
        __syncthreads();
        if (kq == 0) {
            const f32x4* src = red + nh * 2048 + lane;
#pragma unroll
            for (int mt = 0; mt < 4; ++mt)
#pragma unroll
                for (int nt = 0; nt < 2; ++nt)
#pragma unroll
                    for (int sub = 0; sub < 4; ++sub) {
                        f32x4 v = src[(mt * 8 + nt * 4 + sub) * 64];
#pragma unroll
                        for (int i = 0; i < 4; ++i)
                            acc[mt][nt][sub * 4 + i] += v[i];
                    }
        }
        __syncthreads();
    }

    // ---- epilogue (kq==0 waves): alpha*acc + bias ----
    if (kq == 0) {
#pragma unroll
        for (int nt = 0; nt < 2; ++nt) {
            int ncol = n0 + nh * 64 + nt * 32 + (lane & 31);
            float av = alpha[ncol];
            float bv = bias[ncol];
#pragma unroll
            for (int mt = 0; mt < 4; ++mt) {
#pragma unroll
                for (int r = 0; r < 16; ++r) {
                    int row = m0 + mt * 32 + (r & 3) + 8 * (r >> 2) + 4 * (lane >> 5);
                    Out[(size_t)row * OUT_F + ncol] = acc[mt][nt][r] * av + bv;
                }
            }
        }
    }
}

// ---- naive fallback (workspace too small; correctness only) ----
__global__ void ternary_naive(const float* __restrict__ X, const u32* __restrict__ W2,
                              const float* __restrict__ alpha, const float* __restrict__ bias,
                              float* __restrict__ Out) {
    int o  = blockIdx.x * 64 + (threadIdx.x & 63);
    int tk = blockIdx.y * 4 + (threadIdx.x >> 6);
    const float* x = X + (size_t)tk * IN_F;
    const u32* w = W2 + (size_t)o * KPACK;
    float s = 0.f;
    for (int d = 0; d < KPACK; ++d) {
        u32 b = w[d] & 0xFFu;
        const float* xp = x + d * 4;
#pragma unroll
        for (int j = 0; j < 4; ++j) {
            u32 c = (b >> (2 * j)) & 3u;
            float wv = (c == 2u) ? 1.f : ((c == 0u) ? -1.f : 0.f);
            s += xp[j] * wv;
        }
    }
    Out[(size_t)tk * OUT_F + o] = s * alpha[o] + bias[o];
}

extern "C" void kernel_launch(void* const* d_in, const int* in_sizes, int n_in,
                              void* d_out, int out_size, void* d_ws, size_t ws_size,
                              hipStream_t stream) {
    const float* x = (const float*)d_in[0];
    const u32* w2 = (const u32*)d_in[1];
    const float* alpha = (const float*)d_in[2];
    const float* bias  = (const float*)d_in[3];
    float* out = (float*)d_out;

    const size_t xb_bytes  = (size_t)TOKENS * IN_F * sizeof(u16);  // 4 MB
    const size_t w10_bytes = (size_t)OUT_F * IN_F / 4;             // 8 MB

    if (ws_size >= xb_bytes + w10_bytes) {
        u16* xb = (u16*)d_ws;
        uint4* w10 = (uint4*)((char*)d_ws + xb_bytes);
        prep<<<dim3(64, 9), 256, 0, stream>>>(x, xb, w2, w10);
        ternary_gemm14<<<dim3(TOKENS / TMB, OUT_F / TNB), 512, 0, stream>>>(xb, w10, alpha, bias, out);
    } else {
        ternary_naive<<<dim3(OUT_F / 64, TOKENS / 4), 256, 0, stream>>>(x, w2, alpha, bias, out);
    }
}